// Round 15
// baseline (292.498 us; speedup 1.0000x reference)
//
#include <hip/hip_runtime.h>
#include <cmath>

namespace {
constexpr int BPTS  = 16384;
constexpr int NPOSE = 32;
constexpr int KV    = 8;
constexpr int HD    = 256;
constexpr int TM    = 128;      // points per block (mlp)
constexpr float TAU = 0.04f;    // argmin ambiguity threshold (~2.5x observed max err)

constexpr size_t OFF_XLOCAL = 0;
constexpr size_t OFF_XLA    = (size_t)BPTS * 3;
constexpr size_t OFF_MINENC = OFF_XLA + (size_t)NPOSE * BPTS * 3;
constexpr size_t OFF_POSEQ  = OFF_MINENC + (size_t)BPTS * NPOSE;
constexpr size_t OFF_CLASS  = OFF_POSEQ + (size_t)BPTS * 16;
constexpr size_t OFF_PRED   = OFF_CLASS + (size_t)BPTS;
constexpr size_t OFF_VECQ   = OFF_PRED + (size_t)BPTS * NPOSE;

// workspace: 16x16 f16 weight fragments (hi/lo, for 3-term recompute),
// reverify structures, then 32x32-layout hi fragments (for the main mlp).
constexpr size_t WS_W0H = 0;         // f16 element offsets
constexpr size_t WS_W0L = 16384;
constexpr size_t WS_W1H = 32768;
constexpr size_t WS_W1L = 98304;
constexpr size_t WS_W2H = 163840;
constexpr size_t WS_W2L = 229376;
constexpr size_t WB_END   = 589824;              // bytes
constexpr size_t CNT_B    = WB_END;
constexpr size_t PAIRS_B  = WB_END + 1024;
constexpr int    PAIR_CAP = 65536;
constexpr size_t EXACT_B  = PAIRS_B + (size_t)PAIR_CAP * 8;
constexpr size_t WS32_B   = EXACT_B + (size_t)BPTS * NPOSE * 4;   // byte offset
// f16 element offsets (relative to wf base) of the 32x32-layout frags:
constexpr size_t WS32_W0 = WS32_B / 2;                 // 8 tiles * 3 ks * 512
constexpr size_t WS32_W1 = WS32_W0 + 12288;            // 8 tiles * 16 ks * 512
constexpr size_t WS32_W2 = WS32_W1 + 65536;

// LDS layout (mlp): h 64KB | feat [128][48] 12KB | predp [128][8] 4KB = 80KB
constexpr int LDS_FEAT  = 65536;
constexpr int LDS_PREDP = 65536 + 12288;
constexpr int LDS_TOTAL = 65536 + 12288 + 4096;        // 81920 = 2 blocks/CU exact
}

typedef _Float16 f16;
typedef __attribute__((ext_vector_type(4)))  _Float16 f16x4;
typedef __attribute__((ext_vector_type(8)))  _Float16 f16x8;
typedef __attribute__((ext_vector_type(4)))  float    f32x4;
typedef __attribute__((ext_vector_type(16))) float    f32x16;

#define MFMA16(a, b, c) __builtin_amdgcn_mfma_f32_16x16x32_f16((a), (b), (c), 0, 0, 0)
#define MFMA32(a, b, c) __builtin_amdgcn_mfma_f32_32x32x16_f16((a), (b), (c), 0, 0, 0)

// ---- merged weight prep (+ cnt zero).
// 16x16 frags: idx=((cht*KC+kc)*64+l)*8+e -> W[k=kc*32+(l>>4)*8+e][ch=cht*16+(l&15)]
// 32x32 frags: idx=((tile*KS+ks)*64+l)*8+e -> W[k=ks*16+(l>>5)*8+e][ch=tile*32+(l&31)]
__global__ __launch_bounds__(256)
void prep_all(const float* __restrict__ w0, const float* __restrict__ w1,
              const float* __restrict__ w2, f16* __restrict__ wf, int* __restrict__ cnt)
{
    const int bid = blockIdx.x, tid = threadIdx.x;
    if (bid == 0 && tid == 0) *cnt = 0;
    if (bid < 64) {                       // w0 16x16: KC=2
        int i = bid * 256 + tid;
        int e = i & 7, l = (i >> 3) & 63, kc = (i >> 9) & 1, nt = i >> 10;
        int k = kc * 32 + ((l >> 4) << 3) + e;
        int col = nt * 16 + (l & 15);
        float v = (k < 39) ? w0[k * HD + col] : 0.f;
        f16 hi = (f16)v;
        wf[WS_W0H + i] = hi;
        wf[WS_W0L + i] = (f16)(v - (float)hi);
    } else if (bid < 576) {               // w1/w2 16x16: KC=8
        const bool is1 = bid < 320;
        const float* w = is1 ? w1 : w2;
        int i = (bid - (is1 ? 64 : 320)) * 256 + tid;
        int e = i & 7, l = (i >> 3) & 63, kc = (i >> 9) & 7, nt = i >> 12;
        int k = kc * 32 + ((l >> 4) << 3) + e;
        int col = nt * 16 + (l & 15);
        float v = w[k * HD + col];
        f16 hi = (f16)v;
        wf[(is1 ? WS_W1H : WS_W2H) + i] = hi;
        wf[(is1 ? WS_W1L : WS_W2L) + i] = (f16)(v - (float)hi);
    } else if (bid < 624) {               // w0 32x32: KS=3 (k padded to 48)
        int i = (bid - 576) * 256 + tid;  // 12288 total
        int e = i & 7, l = (i >> 3) & 63, r = i >> 9;
        int ks = r % 3, tile = r / 3;
        int k  = ks * 16 + ((l >> 5) << 3) + e;
        int ch = tile * 32 + (l & 31);
        wf[WS32_W0 + i] = (f16)((k < 39) ? w0[k * HD + ch] : 0.f);
    } else {                              // w1/w2 32x32: KS=16
        const bool is1 = bid < 880;
        const float* w = is1 ? w1 : w2;
        int i = (bid - (is1 ? 624 : 880)) * 256 + tid;   // 65536 each
        int e = i & 7, l = (i >> 3) & 63, r = i >> 9;
        int ks = r & 15, tile = r >> 4;
        int k  = ks * 16 + ((l >> 5) << 3) + e;
        int ch = tile * 32 + (l & 31);
        wf[(is1 ? WS32_W1 : WS32_W2) + i] = (f16)w[k * HD + ch];
    }
}

// swizzled byte address in the 512B full-width row: p row, cbyte 0..511
__device__ __forceinline__ int bswz(int p, int cbyte) {
    return p * 512 + (cbyte ^ ((p & 15) << 4));
}

// TM=128 full-pass, 1-term, 32x32x16 MFMA (half the MFMA instrs of 16x16x32,
// ~20% better pipe efficiency). (512,4) = 128-reg budget: acc 64 AGPR + ~55
// arch; #pragma unroll 1 on ks keeps live arch regs low (r9/r12 lesson).
__global__ __launch_bounds__(512, 4)
void mlp_kernel(const float* __restrict__ x_world,
                const float* __restrict__ inv_poses,
                const float* __restrict__ b0, const float* __restrict__ b1,
                const float* __restrict__ b2, const float* __restrict__ w3,
                const float* __restrict__ b3, const f16* __restrict__ wf,
                float* __restrict__ out)
{
    __shared__ char lds[LDS_TOTAL];     // h[128][256] f16 | feat[128][48] | predp

    f16*   feath = (f16*)(lds + LDS_FEAT);      // stride 48 f16 (96B)
    float* predp = (float*)(lds + LDS_PREDP);   // [128][8]

    const int tid  = threadIdx.x;
    const int lane = tid & 63;
    const int wv   = tid >> 6;          // wave id 0..7 = 32-channel tile
    const int l31  = lane & 31;
    const int hi32 = lane >> 5;         // 0/1

    const int bid   = blockIdx.x;
    const int n_idx = bid >> 7;         // 128 blocks per pose
    const int bbase = (bid & 127) * TM;

    // ---- pose transform + positional encoding (4 threads per point) ----
    {
        const int p   = tid >> 2;       // 0..127
        const int sub = tid & 3;
        const int b   = bbase + p;
        const float xw0 = x_world[b*3+0], xw1 = x_world[b*3+1], xw2 = x_world[b*3+2];
        const float* P = inv_poses + n_idx * 16;
        float xl[3];
        #pragma unroll
        for (int x = 0; x < 3; ++x)
            xl[x] = P[x*4+3] + P[x*4+0]*xw0 + P[x*4+1]*xw1 + P[x*4+2]*xw2;

        auto put = [&](int c, float v) { feath[p*48 + c] = (f16)v; };
        if (sub == 0) {
            float* xla = out + OFF_XLA + ((size_t)n_idx * BPTS + b) * 3;
            #pragma unroll
            for (int x = 0; x < 3; ++x) { xla[x] = xl[x]; put(x, xl[x]); }
            put(39, 0.f);               // k-pad
        }
        if (sub == 1) {                 // zero k 40..47 (B garbage would NaN-poison)
            const f16x8 z = {};
            *(f16x8*)(feath + p*48 + 40) = z;
        }
        #pragma unroll
        for (int t = 0; t < 3; ++t) {   // 12 sin/cos jobs, 3 per sub (fast-math:
            int j = sub * 3 + t;        // err ~1e-6 << f16 rounding; exact path
            int o = j >> 1, fn = j & 1; // (recompute) keeps libm sinf/cosf)
            float s = (float)(1 << o);
            #pragma unroll
            for (int x = 0; x < 3; ++x) {
                float a = xl[x] * s;
                put(3 + 6*o + 3*fn + x, fn ? __cosf(a) : __sinf(a));
            }
        }
    }
    __syncthreads();

    f32x16 acc[4];                      // [pt-tile]: 32 ch x 128 pts (64 AGPR)
    // D layout (m101-verified): col = n = pt = lane&31;
    // row = m = ch = (reg&3) + 8*(reg>>2) + 4*(lane>>5)

    auto init_bias = [&](const float* bias) {
        #pragma unroll
        for (int rg = 0; rg < 4; ++rg) {
            f32x4 bv = *(const f32x4*)(bias + wv*32 + rg*8 + hi32*4);
            #pragma unroll
            for (int t = 0; t < 4; ++t)
                #pragma unroll
                for (int j = 0; j < 4; ++j)
                    acc[t][rg*4+j] = bv[j];
        }
    };
    auto st_all = [&]() {               // relu+pack -> h[pt][ch] (16 b64 writes)
        #pragma unroll
        for (int t = 0; t < 4; ++t) {
            int prow = t*32 + l31;
            #pragma unroll
            for (int rg = 0; rg < 4; ++rg) {
                int cbyte = wv*64 + rg*16 + hi32*8;
                f16x4 v = {(f16)fmaxf(acc[t][rg*4+0],0.f),
                           (f16)fmaxf(acc[t][rg*4+1],0.f),
                           (f16)fmaxf(acc[t][rg*4+2],0.f),
                           (f16)fmaxf(acc[t][rg*4+3],0.f)};
                *(f16x4*)(lds + bswz(prow, cbyte)) = v;
            }
        }
    };
    // B-read base: row*512 ^ ((l>>5)*16) ^ ((l&15)<<4), then ^ (ks<<5) per step
    int baseB[4];
    #pragma unroll
    for (int t = 0; t < 4; ++t)
        baseB[t] = ((t*32 + l31) * 512) ^ (hi32 * 16) ^ ((lane & 15) << 4);

    auto hidden_accum = [&](const f16* wf32) {
        const f16* wp = wf32 + ((size_t)wv * 16 * 512) + lane * 8;
        #pragma unroll 1
        for (int ks = 0; ks < 16; ++ks) {
            f16x8 wA = *(const f16x8*)(wp + ks * 512);
            #pragma unroll
            for (int t = 0; t < 4; ++t) {
                f16x8 bB = *(const f16x8*)(lds + (baseB[t] ^ (ks << 5)));
                acc[t] = MFMA32(wA, bB, acc[t]);
            }
        }
    };

    // ---- layer 0: feat(39, padded 48) -> acc ----
    init_bias(b0);
    {
        const f16* wp = wf + WS32_W0 + ((size_t)wv * 3 * 512) + lane * 8;
        #pragma unroll
        for (int ks = 0; ks < 3; ++ks) {
            f16x8 wA = *(const f16x8*)(wp + ks * 512);
            #pragma unroll
            for (int t = 0; t < 4; ++t) {
                int p = t*32 + l31;
                f16x8 bB = *(const f16x8*)(feath + p*48 + ks*16 + hi32*8);
                acc[t] = MFMA32(wA, bB, acc[t]);
            }
        }
    }
    st_all();                           // h region disjoint from feath
    __syncthreads();                    // h0 complete & visible

    // ---- layer 1 ----
    init_bias(b1);
    hidden_accum(wf + WS32_W1);
    __syncthreads();                    // all waves done reading h0
    st_all();
    __syncthreads();                    // h1 complete & visible

    // ---- layer 2 + layer 3 fused: pred from registers, no stores ----
    init_bias(b2);
    hidden_accum(wf + WS32_W2);
    {
        float pp[4] = {};
        #pragma unroll
        for (int rg = 0; rg < 4; ++rg) {
            f32x4 w3v = *(const f32x4*)(w3 + wv*32 + rg*8 + hi32*4);
            #pragma unroll
            for (int t = 0; t < 4; ++t)
                #pragma unroll
                for (int j = 0; j < 4; ++j)
                    pp[t] = fmaf(fmaxf(acc[t][rg*4+j], 0.f), w3v[j], pp[t]);
        }
        #pragma unroll
        for (int t = 0; t < 4; ++t) pp[t] += __shfl_xor(pp[t], 32);
        if (hi32 == 0) {
            #pragma unroll
            for (int t = 0; t < 4; ++t)
                predp[(t*32 + l31) * 8 + wv] = pp[t];
        }
    }
    __syncthreads();
    if (tid < TM) {
        float s = b3[0];
        #pragma unroll
        for (int j = 0; j < 8; ++j) s += predp[tid * 8 + j];
        out[OFF_PRED + (size_t)(bbase + tid) * NPOSE + n_idx] = s;
    }
}

// per-point output writer (shared by select & fixup)
__device__ __forceinline__ void write_point(int b, int idx,
                                            const float* __restrict__ x_world,
                                            const float* __restrict__ inv_poses,
                                            const float* __restrict__ vector,
                                            float* __restrict__ out)
{
    float* me = out + OFF_MINENC + (size_t)b * NPOSE;
    #pragma unroll
    for (int n = 0; n < NPOSE; ++n) me[n] = (n == idx) ? 1.f : 0.f;

    const float* P = inv_poses + idx * 16;
    float* pq = out + OFF_POSEQ + (size_t)b * 16;
    #pragma unroll
    for (int m = 0; m < 16; ++m) pq[m] = P[m];

    const float xw0 = x_world[b*3+0], xw1 = x_world[b*3+1], xw2 = x_world[b*3+2];
    float* xl = out + OFF_XLOCAL + (size_t)b * 3;
    #pragma unroll
    for (int x = 0; x < 3; ++x)
        xl[x] = P[x*4+3] + P[x*4+0]*xw0 + P[x*4+1]*xw1 + P[x*4+2]*xw2;

    out[OFF_CLASS + b] = (float)idx;

    const float* vq = vector + idx * KV;
    float* ov = out + OFF_VECQ + (size_t)b * KV;
    #pragma unroll
    for (int m = 0; m < KV; ++m) ov[m] = vq[m];
}

__global__ __launch_bounds__(256)
void select_kernel(const float* __restrict__ x_world,
                   const float* __restrict__ inv_poses,
                   const float* __restrict__ vector,
                   float* __restrict__ out,
                   int* __restrict__ cnt, int2* __restrict__ pairs,
                   float* __restrict__ exact)
{
    const int b = blockIdx.x * 256 + threadIdx.x;
    if (b >= BPTS) return;

    const float* pr = out + OFF_PRED + (size_t)b * NPOSE;
    float best = pr[0], best2 = 3.4e38f;
    int idx = 0;
    #pragma unroll
    for (int n = 1; n < NPOSE; ++n) {
        float v = pr[n];
        if (v < best) { best2 = best; best = v; idx = n; }
        else if (v < best2) { best2 = v; }
    }

    if (best2 - best >= TAU) {
        write_point(b, idx, x_world, inv_poses, vector, out);
    } else {
        #pragma unroll
        for (int n = 0; n < NPOSE; ++n) {
            float v = pr[n];
            if (v < best + TAU) {
                exact[b * NPOSE + n] = v;
                int slot = atomicAdd(cnt, 1);
                if (slot < PAIR_CAP) pairs[slot] = make_int2(b, n);
            }
        }
    }
}

// ---- high-accuracy recompute for flagged pairs: 3-term split-f16 MFMA (16x16).
// 64 pairs/block, 8 waves x disjoint channel groups (weights once/block).
// Error ~ sum(wl*al) ~ 1e-5: fp32-class for argmin purposes.
__global__ __launch_bounds__(512, 4)
void recompute_kernel(const float* __restrict__ x_world,
                      const float* __restrict__ inv_poses,
                      const float* __restrict__ b0, const float* __restrict__ b1,
                      const float* __restrict__ b2, const float* __restrict__ w3,
                      const float* __restrict__ b3, const f16* __restrict__ wf,
                      const int* __restrict__ cnt, const int2* __restrict__ pairs,
                      float* __restrict__ exact)
{
    // plane_hi 32KB | plane_lo 32KB | feath 5KB | featl 5KB  (rows are 64 points)
    __shared__ char  lds[75776];
    __shared__ float predp[64][8];
    __shared__ int2  pl[64];

    f16* feath = (f16*)(lds + 65536);
    f16* featl = (f16*)(lds + 65536 + 5120);

    const int tid  = threadIdx.x;
    const int lane = tid & 63;
    const int wv   = tid >> 6;
    const int l15  = lane & 15;
    const int g    = lane >> 4;
    const int total = min(*cnt, PAIR_CAP);

    f32x4 acc[2][4];                    // [c2][q]: 32 ch x 64 rows (32 AGPR)

    auto init_bias = [&](const float* bias) {
        #pragma unroll
        for (int c2 = 0; c2 < 2; ++c2) {
            f32x4 bv = *(const f32x4*)(bias + (wv + c2*8) * 16 + g * 4);
            #pragma unroll
            for (int q = 0; q < 4; ++q) acc[c2][q] = bv;
        }
    };
    auto packpair = [&](f32x4 a, f16x4& hv, f16x4& lv) {
        float v0 = fmaxf(a[0],0.f), v1 = fmaxf(a[1],0.f);
        float v2 = fmaxf(a[2],0.f), v3 = fmaxf(a[3],0.f);
        f16 h0=(f16)v0, h1=(f16)v1, h2=(f16)v2, h3=(f16)v3;
        hv = (f16x4){h0,h1,h2,h3};
        lv = (f16x4){(f16)(v0-(float)h0),(f16)(v1-(float)h1),
                     (f16)(v2-(float)h2),(f16)(v3-(float)h3)};
    };
    auto st_all2 = [&]() {              // relu+split both planes
        #pragma unroll
        for (int c2 = 0; c2 < 2; ++c2)
            #pragma unroll
            for (int q = 0; q < 4; ++q) {
                int byte = bswz(q * 16 + l15, c2 * 256 + wv * 32 + g * 8);
                f16x4 hv, lv;
                packpair(acc[c2][q], hv, lv);
                *(f16x4*)(lds + byte)         = hv;
                *(f16x4*)(lds + 32768 + byte) = lv;
            }
    };
    auto hidden3 = [&](const f16* wfh, const f16* wfl) {
        const f16* wph0 = wfh + ((size_t)(wv    ) * 4096 + lane * 8);
        const f16* wpl0 = wfl + ((size_t)(wv    ) * 4096 + lane * 8);
        const f16* wph1 = wfh + ((size_t)(wv + 8) * 4096 + lane * 8);
        const f16* wpl1 = wfl + ((size_t)(wv + 8) * 4096 + lane * 8);
        #pragma unroll 1
        for (int kcg = 0; kcg < 8; ++kcg) {
            f16x8 wh0 = *(const f16x8*)(wph0 + kcg * 512);
            f16x8 wl0 = *(const f16x8*)(wpl0 + kcg * 512);
            f16x8 wh1 = *(const f16x8*)(wph1 + kcg * 512);
            f16x8 wl1 = *(const f16x8*)(wpl1 + kcg * 512);
            #pragma unroll
            for (int q = 0; q < 4; ++q) {
                int byte = bswz(q * 16 + l15, kcg * 64 + g * 16);
                f16x8 bh = *(const f16x8*)(lds + byte);
                f16x8 bl = *(const f16x8*)(lds + 32768 + byte);
                acc[0][q] = MFMA16(wh0, bh, acc[0][q]);
                acc[0][q] = MFMA16(wl0, bh, acc[0][q]);
                acc[0][q] = MFMA16(wh0, bl, acc[0][q]);
                acc[1][q] = MFMA16(wh1, bh, acc[1][q]);
                acc[1][q] = MFMA16(wl1, bh, acc[1][q]);
                acc[1][q] = MFMA16(wh1, bl, acc[1][q]);
            }
        }
    };

    for (int base = blockIdx.x * 64; base < total; base += gridDim.x * 64) {
        const int nrows = min(64, total - base);
        if (tid < 64) pl[tid] = (tid < nrows) ? pairs[base + tid] : make_int2(0, 0);
        __syncthreads();
        // ---- embed flagged pairs (8 threads per row), hi+lo planes ----
        {
            const int p   = tid >> 3;
            const int sub = tid & 7;
            const int2 pp = pl[p];
            const int b = pp.x;
            const float xw0 = x_world[b*3+0], xw1 = x_world[b*3+1], xw2 = x_world[b*3+2];
            const float* P = inv_poses + pp.y * 16;
            float xl[3];
            #pragma unroll
            for (int x = 0; x < 3; ++x)
                xl[x] = P[x*4+3] + P[x*4+0]*xw0 + P[x*4+1]*xw1 + P[x*4+2]*xw2;
            auto put = [&](int c, float v) {
                f16 hi = (f16)v;
                feath[p*40 + c] = hi;
                featl[p*40 + c] = (f16)(v - (float)hi);
            };
            if (sub == 0) {
                #pragma unroll
                for (int x = 0; x < 3; ++x) put(x, xl[x]);
                put(39, 0.f);
            }
            #pragma unroll
            for (int t = 0; t < 2; ++t) {
                int j = sub + 8*t;
                if (j < 12) {
                    int o = j >> 1, fn = j & 1;
                    float s = (float)(1 << o);
                    #pragma unroll
                    for (int x = 0; x < 3; ++x) {
                        float a = xl[x] * s;
                        put(3 + 6*o + 3*fn + x, fn ? cosf(a) : sinf(a));
                    }
                }
            }
        }
        __syncthreads();

        // ---- layer 0 (3-term) ----
        init_bias(b0);
        {
            const f16x8 z = {};
            #pragma unroll
            for (int kc = 0; kc < 2; ++kc) {
                f16x8 wh0 = *(const f16x8*)(wf + WS_W0H + ((wv*2     + kc)*64 + lane)*8);
                f16x8 wl0 = *(const f16x8*)(wf + WS_W0L + ((wv*2     + kc)*64 + lane)*8);
                f16x8 wh1 = *(const f16x8*)(wf + WS_W0H + (((wv+8)*2 + kc)*64 + lane)*8);
                f16x8 wl1 = *(const f16x8*)(wf + WS_W0L + (((wv+8)*2 + kc)*64 + lane)*8);
                #pragma unroll
                for (int q = 0; q < 4; ++q) {
                    int p = q * 16 + l15;
                    f16x8 ah, al;
                    if (kc == 0) {
                        ah = *(const f16x8*)&feath[p*40 + g*8];
                        al = *(const f16x8*)&featl[p*40 + g*8];
                    } else if (g == 0) {
                        ah = *(const f16x8*)&feath[p*40 + 32];
                        al = *(const f16x8*)&featl[p*40 + 32];
                    } else { ah = z; al = z; }
                    acc[0][q] = MFMA16(wh0, ah, acc[0][q]);
                    acc[0][q] = MFMA16(wl0, ah, acc[0][q]);
                    acc[0][q] = MFMA16(wh0, al, acc[0][q]);
                    acc[1][q] = MFMA16(wh1, ah, acc[1][q]);
                    acc[1][q] = MFMA16(wl1, ah, acc[1][q]);
                    acc[1][q] = MFMA16(wh1, al, acc[1][q]);
                }
            }
        }
        st_all2();                      // planes last read 2 syncs ago: safe
        __syncthreads();

        // ---- layer 1 ----
        init_bias(b1);
        hidden3(wf + WS_W1H, wf + WS_W1L);
        __syncthreads();
        st_all2();
        __syncthreads();

        // ---- layer 2 + layer 3 ----
        init_bias(b2);
        hidden3(wf + WS_W2H, wf + WS_W2L);
        {
            float pp4[4] = {};
            #pragma unroll
            for (int c2 = 0; c2 < 2; ++c2) {
                f32x4 wvv = *(const f32x4*)(w3 + (wv + c2*8) * 16 + g * 4);
                #pragma unroll
                for (int q = 0; q < 4; ++q)
                    #pragma unroll
                    for (int r = 0; r < 4; ++r)
                        pp4[q] = fmaf(fmaxf(acc[c2][q][r], 0.f), wvv[r], pp4[q]);
            }
            #pragma unroll
            for (int q = 0; q < 4; ++q) {
                pp4[q] += __shfl_xor(pp4[q], 16);
                pp4[q] += __shfl_xor(pp4[q], 32);
            }
            if (g == 0) {
                #pragma unroll
                for (int q = 0; q < 4; ++q)
                    predp[q * 16 + l15][wv] = pp4[q];
            }
        }
        __syncthreads();
        if (tid < nrows) {
            float s = b3[0];
            #pragma unroll
            for (int j = 0; j < 8; ++j) s += predp[tid][j];
            exact[pl[tid].x * NPOSE + pl[tid].y] = s;
        }
        __syncthreads();                // protect predp/pl before next chunk
    }
}

__global__ __launch_bounds__(256)
void fixup_kernel(const float* __restrict__ x_world,
                  const float* __restrict__ inv_poses,
                  const float* __restrict__ vector,
                  float* __restrict__ out,
                  const float* __restrict__ exact)
{
    const int b = blockIdx.x * 256 + threadIdx.x;
    if (b >= BPTS) return;

    const float* pr = out + OFF_PRED + (size_t)b * NPOSE;
    float best = pr[0], best2 = 3.4e38f;
    #pragma unroll
    for (int n = 1; n < NPOSE; ++n) {
        float v = pr[n];
        if (v < best) { best2 = best; best = v; }
        else if (v < best2) { best2 = v; }
    }
    if (best2 - best >= TAU) return;

    float ebest = 3.4e38f;
    int idx = 0;
    #pragma unroll
    for (int n = 0; n < NPOSE; ++n) {
        if (pr[n] < best + TAU) {
            float v = exact[b * NPOSE + n];
            if (v < ebest) { ebest = v; idx = n; }
        }
    }
    write_point(b, idx, x_world, inv_poses, vector, out);
}

extern "C" void kernel_launch(void* const* d_in, const int* in_sizes, int n_in,
                              void* d_out, int out_size, void* d_ws, size_t ws_size,
                              hipStream_t stream)
{
    const float* x_world   = (const float*)d_in[0];
    const float* inv_poses = (const float*)d_in[1];
    const float* vector    = (const float*)d_in[2];
    const float* w0 = (const float*)d_in[3];
    const float* b0 = (const float*)d_in[4];
    const float* w1 = (const float*)d_in[5];
    const float* b1 = (const float*)d_in[6];
    const float* w2 = (const float*)d_in[7];
    const float* b2 = (const float*)d_in[8];
    const float* w3 = (const float*)d_in[9];
    const float* b3 = (const float*)d_in[10];
    float* out = (float*)d_out;

    char*  ws    = (char*)d_ws;
    f16*   wf    = (f16*)ws;
    int*   cnt   = (int*)(ws + CNT_B);
    int2*  pairs = (int2*)(ws + PAIRS_B);
    float* exact = (float*)(ws + EXACT_B);

    prep_all<<<dim3(1136), dim3(256), 0, stream>>>(w0, w1, w2, wf, cnt);

    mlp_kernel<<<dim3(NPOSE * BPTS / TM), dim3(512), 0, stream>>>(
        x_world, inv_poses, b0, b1, b2, w3, b3, wf, out);
    select_kernel<<<dim3(BPTS / 256), dim3(256), 0, stream>>>(
        x_world, inv_poses, vector, out, cnt, pairs, exact);
    recompute_kernel<<<dim3(512), dim3(512), 0, stream>>>(
        x_world, inv_poses, b0, b1, b2, w3, b3, wf, cnt, pairs, exact);
    fixup_kernel<<<dim3(BPTS / 256), dim3(256), 0, stream>>>(
        x_world, inv_poses, vector, out, exact);
}

// Round 16
// 213.653 us; speedup vs baseline: 1.3690x; 1.3690x over previous
//
#include <hip/hip_runtime.h>
#include <cmath>

namespace {
constexpr int BPTS  = 16384;
constexpr int NPOSE = 32;
constexpr int KV    = 8;
constexpr int HD    = 256;
constexpr int TM    = 128;      // points per block (mlp)
constexpr float TAU = 0.04f;    // argmin ambiguity threshold (~2.5x observed max err)

constexpr size_t OFF_XLOCAL = 0;
constexpr size_t OFF_XLA    = (size_t)BPTS * 3;
constexpr size_t OFF_MINENC = OFF_XLA + (size_t)NPOSE * BPTS * 3;
constexpr size_t OFF_POSEQ  = OFF_MINENC + (size_t)BPTS * NPOSE;
constexpr size_t OFF_CLASS  = OFF_POSEQ + (size_t)BPTS * 16;
constexpr size_t OFF_PRED   = OFF_CLASS + (size_t)BPTS;
constexpr size_t OFF_VECQ   = OFF_PRED + (size_t)BPTS * NPOSE;

// workspace: 16x16 f16 weight fragments (hi/lo, for 3-term recompute),
// reverify structures, then 32x32-layout hi fragments (for the main mlp).
constexpr size_t WS_W0H = 0;         // f16 element offsets
constexpr size_t WS_W0L = 16384;
constexpr size_t WS_W1H = 32768;
constexpr size_t WS_W1L = 98304;
constexpr size_t WS_W2H = 163840;
constexpr size_t WS_W2L = 229376;
constexpr size_t WB_END   = 589824;              // bytes
constexpr size_t CNT_B    = WB_END;
constexpr size_t PAIRS_B  = WB_END + 1024;
constexpr int    PAIR_CAP = 65536;
constexpr size_t EXACT_B  = PAIRS_B + (size_t)PAIR_CAP * 8;
constexpr size_t WS32_B   = EXACT_B + (size_t)BPTS * NPOSE * 4;   // byte offset
// f16 element offsets (relative to wf base) of the 32x32-layout frags:
constexpr size_t WS32_W0 = WS32_B / 2;                 // 8 tiles * 3 ks * 512
constexpr size_t WS32_W1 = WS32_W0 + 12288;            // 8 tiles * 16 ks * 512
constexpr size_t WS32_W2 = WS32_W1 + 65536;

// LDS layout (mlp): h 64KB | feat [128][48] 12KB | predp [128][8] 4KB = 80KB
constexpr int LDS_FEAT  = 65536;
constexpr int LDS_PREDP = 65536 + 12288;
constexpr int LDS_TOTAL = 65536 + 12288 + 4096;        // 81920 = 2 blocks/CU exact
}

typedef _Float16 f16;
typedef __attribute__((ext_vector_type(4)))  _Float16 f16x4;
typedef __attribute__((ext_vector_type(8)))  _Float16 f16x8;
typedef __attribute__((ext_vector_type(4)))  float    f32x4;
typedef __attribute__((ext_vector_type(16))) float    f32x16;

#define MFMA16(a, b, c) __builtin_amdgcn_mfma_f32_16x16x32_f16((a), (b), (c), 0, 0, 0)
#define MFMA32(a, b, c) __builtin_amdgcn_mfma_f32_32x32x16_f16((a), (b), (c), 0, 0, 0)

// ---- merged weight prep (+ cnt zero).
// 16x16 frags: idx=((cht*KC+kc)*64+l)*8+e -> W[k=kc*32+(l>>4)*8+e][ch=cht*16+(l&15)]
// 32x32 frags: idx=((tile*KS+ks)*64+l)*8+e -> W[k=ks*16+(l>>5)*8+e][ch=tile*32+(l&31)]
__global__ __launch_bounds__(256)
void prep_all(const float* __restrict__ w0, const float* __restrict__ w1,
              const float* __restrict__ w2, f16* __restrict__ wf, int* __restrict__ cnt)
{
    const int bid = blockIdx.x, tid = threadIdx.x;
    if (bid == 0 && tid == 0) *cnt = 0;
    if (bid < 64) {                       // w0 16x16: KC=2
        int i = bid * 256 + tid;
        int e = i & 7, l = (i >> 3) & 63, kc = (i >> 9) & 1, nt = i >> 10;
        int k = kc * 32 + ((l >> 4) << 3) + e;
        int col = nt * 16 + (l & 15);
        float v = (k < 39) ? w0[k * HD + col] : 0.f;
        f16 hi = (f16)v;
        wf[WS_W0H + i] = hi;
        wf[WS_W0L + i] = (f16)(v - (float)hi);
    } else if (bid < 576) {               // w1/w2 16x16: KC=8
        const bool is1 = bid < 320;
        const float* w = is1 ? w1 : w2;
        int i = (bid - (is1 ? 64 : 320)) * 256 + tid;
        int e = i & 7, l = (i >> 3) & 63, kc = (i >> 9) & 7, nt = i >> 12;
        int k = kc * 32 + ((l >> 4) << 3) + e;
        int col = nt * 16 + (l & 15);
        float v = w[k * HD + col];
        f16 hi = (f16)v;
        wf[(is1 ? WS_W1H : WS_W2H) + i] = hi;
        wf[(is1 ? WS_W1L : WS_W2L) + i] = (f16)(v - (float)hi);
    } else if (bid < 624) {               // w0 32x32: KS=3 (k padded to 48)
        int i = (bid - 576) * 256 + tid;  // 12288 total
        int e = i & 7, l = (i >> 3) & 63, r = i >> 9;
        int ks = r % 3, tile = r / 3;
        int k  = ks * 16 + ((l >> 5) << 3) + e;
        int ch = tile * 32 + (l & 31);
        wf[WS32_W0 + i] = (f16)((k < 39) ? w0[k * HD + ch] : 0.f);
    } else {                              // w1/w2 32x32: KS=16
        const bool is1 = bid < 880;
        const float* w = is1 ? w1 : w2;
        int i = (bid - (is1 ? 624 : 880)) * 256 + tid;   // 65536 each
        int e = i & 7, l = (i >> 3) & 63, r = i >> 9;
        int ks = r & 15, tile = r >> 4;
        int k  = ks * 16 + ((l >> 5) << 3) + e;
        int ch = tile * 32 + (l & 31);
        wf[(is1 ? WS32_W1 : WS32_W2) + i] = (f16)w[k * HD + ch];
    }
}

// swizzled byte address in the 512B full-width row: p row, cbyte 0..511
__device__ __forceinline__ int bswz(int p, int cbyte) {
    return p * 512 + (cbyte ^ ((p & 15) << 4));
}

// TM=128 full-pass, 1-term, 32x32x16 MFMA. (512,4) = 128-reg budget: acc 64 AGPR
// + ~55 arch; #pragma unroll 1 on ks keeps live arch regs low (r9/r12 lesson).
// r16: 1-deep weight prefetch (hide L1/L2 latency) + setprio around MFMA cluster.
__global__ __launch_bounds__(512, 4)
void mlp_kernel(const float* __restrict__ x_world,
                const float* __restrict__ inv_poses,
                const float* __restrict__ b0, const float* __restrict__ b1,
                const float* __restrict__ b2, const float* __restrict__ w3,
                const float* __restrict__ b3, const f16* __restrict__ wf,
                float* __restrict__ out)
{
    __shared__ char lds[LDS_TOTAL];     // h[128][256] f16 | feat[128][48] | predp

    f16*   feath = (f16*)(lds + LDS_FEAT);      // stride 48 f16 (96B)
    float* predp = (float*)(lds + LDS_PREDP);   // [128][8]

    const int tid  = threadIdx.x;
    const int lane = tid & 63;
    const int wv   = tid >> 6;          // wave id 0..7 = 32-channel tile
    const int l31  = lane & 31;
    const int hi32 = lane >> 5;         // 0/1

    const int bid   = blockIdx.x;
    const int n_idx = bid >> 7;         // 128 blocks per pose
    const int bbase = (bid & 127) * TM;

    // ---- pose transform + positional encoding (4 threads per point) ----
    {
        const int p   = tid >> 2;       // 0..127
        const int sub = tid & 3;
        const int b   = bbase + p;
        const float xw0 = x_world[b*3+0], xw1 = x_world[b*3+1], xw2 = x_world[b*3+2];
        const float* P = inv_poses + n_idx * 16;
        float xl[3];
        #pragma unroll
        for (int x = 0; x < 3; ++x)
            xl[x] = P[x*4+3] + P[x*4+0]*xw0 + P[x*4+1]*xw1 + P[x*4+2]*xw2;

        auto put = [&](int c, float v) { feath[p*48 + c] = (f16)v; };
        if (sub == 0) {
            float* xla = out + OFF_XLA + ((size_t)n_idx * BPTS + b) * 3;
            #pragma unroll
            for (int x = 0; x < 3; ++x) { xla[x] = xl[x]; put(x, xl[x]); }
            put(39, 0.f);               // k-pad
        }
        if (sub == 1) {                 // zero k 40..47 (B garbage would NaN-poison)
            const f16x8 z = {};
            *(f16x8*)(feath + p*48 + 40) = z;
        }
        #pragma unroll
        for (int t = 0; t < 3; ++t) {   // 12 sin/cos jobs, 3 per sub (fast-math:
            int j = sub * 3 + t;        // err ~1e-6 << f16 rounding; exact path
            int o = j >> 1, fn = j & 1; // (recompute) keeps libm sinf/cosf)
            float s = (float)(1 << o);
            #pragma unroll
            for (int x = 0; x < 3; ++x) {
                float a = xl[x] * s;
                put(3 + 6*o + 3*fn + x, fn ? __cosf(a) : __sinf(a));
            }
        }
    }
    __syncthreads();

    f32x16 acc[4];                      // [pt-tile]: 32 ch x 128 pts (64 AGPR)
    // D layout (m101-verified): col = n = pt = lane&31;
    // row = m = ch = (reg&3) + 8*(reg>>2) + 4*(lane>>5)

    auto init_bias = [&](const float* bias) {
        #pragma unroll
        for (int rg = 0; rg < 4; ++rg) {
            f32x4 bv = *(const f32x4*)(bias + wv*32 + rg*8 + hi32*4);
            #pragma unroll
            for (int t = 0; t < 4; ++t)
                #pragma unroll
                for (int j = 0; j < 4; ++j)
                    acc[t][rg*4+j] = bv[j];
        }
    };
    auto st_all = [&]() {               // relu+pack -> h[pt][ch] (16 b64 writes)
        #pragma unroll
        for (int t = 0; t < 4; ++t) {
            int prow = t*32 + l31;
            #pragma unroll
            for (int rg = 0; rg < 4; ++rg) {
                int cbyte = wv*64 + rg*16 + hi32*8;
                f16x4 v = {(f16)fmaxf(acc[t][rg*4+0],0.f),
                           (f16)fmaxf(acc[t][rg*4+1],0.f),
                           (f16)fmaxf(acc[t][rg*4+2],0.f),
                           (f16)fmaxf(acc[t][rg*4+3],0.f)};
                *(f16x4*)(lds + bswz(prow, cbyte)) = v;
            }
        }
    };
    // B-read base: row*512 ^ ((l>>5)*16) ^ ((row&15)<<4), then ^ (ks<<5) per step
    int baseB[4];
    #pragma unroll
    for (int t = 0; t < 4; ++t)
        baseB[t] = ((t*32 + l31) * 512) ^ (hi32 * 16) ^ ((lane & 15) << 4);

    auto hidden_accum = [&](const f16* wf32) {
        const f16* wp = wf32 + ((size_t)wv * 16 * 512) + lane * 8;
        f16x8 wA = *(const f16x8*)(wp);
        #pragma unroll 1
        for (int ks = 0; ks < 16; ++ks) {
            int nxt = (ks < 15) ? ks + 1 : 15;          // 1-deep prefetch
            f16x8 wN = *(const f16x8*)(wp + nxt * 512);
            __builtin_amdgcn_s_setprio(1);
            #pragma unroll
            for (int t = 0; t < 4; ++t) {
                f16x8 bB = *(const f16x8*)(lds + (baseB[t] ^ (ks << 5)));
                acc[t] = MFMA32(wA, bB, acc[t]);
            }
            __builtin_amdgcn_s_setprio(0);
            wA = wN;
        }
    };

    // ---- layer 0: feat(39, padded 48) -> acc ----
    init_bias(b0);
    {
        const f16* wp = wf + WS32_W0 + ((size_t)wv * 3 * 512) + lane * 8;
        #pragma unroll
        for (int ks = 0; ks < 3; ++ks) {
            f16x8 wA = *(const f16x8*)(wp + ks * 512);
            #pragma unroll
            for (int t = 0; t < 4; ++t) {
                int p = t*32 + l31;
                f16x8 bB = *(const f16x8*)(feath + p*48 + ks*16 + hi32*8);
                acc[t] = MFMA32(wA, bB, acc[t]);
            }
        }
    }
    st_all();                           // h region disjoint from feath
    __syncthreads();                    // h0 complete & visible

    // ---- layer 1 ----
    init_bias(b1);
    hidden_accum(wf + WS32_W1);
    __syncthreads();                    // all waves done reading h0
    st_all();
    __syncthreads();                    // h1 complete & visible

    // ---- layer 2 + layer 3 fused: pred from registers, no stores ----
    init_bias(b2);
    hidden_accum(wf + WS32_W2);
    {
        float pp[4] = {};
        #pragma unroll
        for (int rg = 0; rg < 4; ++rg) {
            f32x4 w3v = *(const f32x4*)(w3 + wv*32 + rg*8 + hi32*4);
            #pragma unroll
            for (int t = 0; t < 4; ++t)
                #pragma unroll
                for (int j = 0; j < 4; ++j)
                    pp[t] = fmaf(fmaxf(acc[t][rg*4+j], 0.f), w3v[j], pp[t]);
        }
        #pragma unroll
        for (int t = 0; t < 4; ++t) pp[t] += __shfl_xor(pp[t], 32);
        if (hi32 == 0) {
            #pragma unroll
            for (int t = 0; t < 4; ++t)
                predp[(t*32 + l31) * 8 + wv] = pp[t];
        }
    }
    __syncthreads();
    if (tid < TM) {
        float s = b3[0];
        #pragma unroll
        for (int j = 0; j < 8; ++j) s += predp[tid * 8 + j];
        out[OFF_PRED + (size_t)(bbase + tid) * NPOSE + n_idx] = s;
    }
}

// per-point output writer (shared by select & fixup)
__device__ __forceinline__ void write_point(int b, int idx,
                                            const float* __restrict__ x_world,
                                            const float* __restrict__ inv_poses,
                                            const float* __restrict__ vector,
                                            float* __restrict__ out)
{
    float* me = out + OFF_MINENC + (size_t)b * NPOSE;
    #pragma unroll
    for (int n = 0; n < NPOSE; ++n) me[n] = (n == idx) ? 1.f : 0.f;

    const float* P = inv_poses + idx * 16;
    float* pq = out + OFF_POSEQ + (size_t)b * 16;
    #pragma unroll
    for (int m = 0; m < 16; ++m) pq[m] = P[m];

    const float xw0 = x_world[b*3+0], xw1 = x_world[b*3+1], xw2 = x_world[b*3+2];
    float* xl = out + OFF_XLOCAL + (size_t)b * 3;
    #pragma unroll
    for (int x = 0; x < 3; ++x)
        xl[x] = P[x*4+3] + P[x*4+0]*xw0 + P[x*4+1]*xw1 + P[x*4+2]*xw2;

    out[OFF_CLASS + b] = (float)idx;

    const float* vq = vector + idx * KV;
    float* ov = out + OFF_VECQ + (size_t)b * KV;
    #pragma unroll
    for (int m = 0; m < KV; ++m) ov[m] = vq[m];
}

__global__ __launch_bounds__(128)
void select_kernel(const float* __restrict__ x_world,
                   const float* __restrict__ inv_poses,
                   const float* __restrict__ vector,
                   float* __restrict__ out,
                   int* __restrict__ cnt, int2* __restrict__ pairs,
                   float* __restrict__ exact)
{
    const int b = blockIdx.x * 128 + threadIdx.x;
    if (b >= BPTS) return;

    const float* pr = out + OFF_PRED + (size_t)b * NPOSE;
    float best = pr[0], best2 = 3.4e38f;
    int idx = 0;
    #pragma unroll
    for (int n = 1; n < NPOSE; ++n) {
        float v = pr[n];
        if (v < best) { best2 = best; best = v; idx = n; }
        else if (v < best2) { best2 = v; }
    }

    if (best2 - best >= TAU) {
        write_point(b, idx, x_world, inv_poses, vector, out);
    } else {
        // one atomic per flagged POINT (G12), not per pair
        unsigned mask = 0;
        int cl = 0;
        #pragma unroll
        for (int n = 0; n < NPOSE; ++n) {
            float v = pr[n];
            if (v < best + TAU) {
                exact[b * NPOSE + n] = v;        // default (overwritten by recompute)
                mask |= 1u << n;
                ++cl;
            }
        }
        int slot = atomicAdd(cnt, cl);
        #pragma unroll
        for (int n = 0; n < NPOSE; ++n) {
            if (mask & (1u << n)) {
                if (slot < PAIR_CAP) pairs[slot] = make_int2(b, n);
                ++slot;
            }
        }
    }
}

// ---- high-accuracy recompute for flagged pairs: 3-term split-f16 MFMA (16x16).
// 64 pairs/block, 8 waves x disjoint channel groups (weights once/block).
// Error ~ sum(wl*al) ~ 1e-5: fp32-class for argmin purposes.
__global__ __launch_bounds__(512, 4)
void recompute_kernel(const float* __restrict__ x_world,
                      const float* __restrict__ inv_poses,
                      const float* __restrict__ b0, const float* __restrict__ b1,
                      const float* __restrict__ b2, const float* __restrict__ w3,
                      const float* __restrict__ b3, const f16* __restrict__ wf,
                      const int* __restrict__ cnt, const int2* __restrict__ pairs,
                      float* __restrict__ exact)
{
    // plane_hi 32KB | plane_lo 32KB | feath 5KB | featl 5KB  (rows are 64 points)
    __shared__ char  lds[75776];
    __shared__ float predp[64][8];
    __shared__ int2  pl[64];

    f16* feath = (f16*)(lds + 65536);
    f16* featl = (f16*)(lds + 65536 + 5120);

    const int tid  = threadIdx.x;
    const int lane = tid & 63;
    const int wv   = tid >> 6;
    const int l15  = lane & 15;
    const int g    = lane >> 4;
    const int total = min(*cnt, PAIR_CAP);

    f32x4 acc[2][4];                    // [c2][q]: 32 ch x 64 rows (32 AGPR)

    auto init_bias = [&](const float* bias) {
        #pragma unroll
        for (int c2 = 0; c2 < 2; ++c2) {
            f32x4 bv = *(const f32x4*)(bias + (wv + c2*8) * 16 + g * 4);
            #pragma unroll
            for (int q = 0; q < 4; ++q) acc[c2][q] = bv;
        }
    };
    auto packpair = [&](f32x4 a, f16x4& hv, f16x4& lv) {
        float v0 = fmaxf(a[0],0.f), v1 = fmaxf(a[1],0.f);
        float v2 = fmaxf(a[2],0.f), v3 = fmaxf(a[3],0.f);
        f16 h0=(f16)v0, h1=(f16)v1, h2=(f16)v2, h3=(f16)v3;
        hv = (f16x4){h0,h1,h2,h3};
        lv = (f16x4){(f16)(v0-(float)h0),(f16)(v1-(float)h1),
                     (f16)(v2-(float)h2),(f16)(v3-(float)h3)};
    };
    auto st_all2 = [&]() {              // relu+split both planes
        #pragma unroll
        for (int c2 = 0; c2 < 2; ++c2)
            #pragma unroll
            for (int q = 0; q < 4; ++q) {
                int byte = bswz(q * 16 + l15, c2 * 256 + wv * 32 + g * 8);
                f16x4 hv, lv;
                packpair(acc[c2][q], hv, lv);
                *(f16x4*)(lds + byte)         = hv;
                *(f16x4*)(lds + 32768 + byte) = lv;
            }
    };
    auto hidden3 = [&](const f16* wfh, const f16* wfl) {
        const f16* wph0 = wfh + ((size_t)(wv    ) * 4096 + lane * 8);
        const f16* wpl0 = wfl + ((size_t)(wv    ) * 4096 + lane * 8);
        const f16* wph1 = wfh + ((size_t)(wv + 8) * 4096 + lane * 8);
        const f16* wpl1 = wfl + ((size_t)(wv + 8) * 4096 + lane * 8);
        #pragma unroll 1
        for (int kcg = 0; kcg < 8; ++kcg) {
            f16x8 wh0 = *(const f16x8*)(wph0 + kcg * 512);
            f16x8 wl0 = *(const f16x8*)(wpl0 + kcg * 512);
            f16x8 wh1 = *(const f16x8*)(wph1 + kcg * 512);
            f16x8 wl1 = *(const f16x8*)(wpl1 + kcg * 512);
            #pragma unroll
            for (int q = 0; q < 4; ++q) {
                int byte = bswz(q * 16 + l15, kcg * 64 + g * 16);
                f16x8 bh = *(const f16x8*)(lds + byte);
                f16x8 bl = *(const f16x8*)(lds + 32768 + byte);
                acc[0][q] = MFMA16(wh0, bh, acc[0][q]);
                acc[0][q] = MFMA16(wl0, bh, acc[0][q]);
                acc[0][q] = MFMA16(wh0, bl, acc[0][q]);
                acc[1][q] = MFMA16(wh1, bh, acc[1][q]);
                acc[1][q] = MFMA16(wl1, bh, acc[1][q]);
                acc[1][q] = MFMA16(wh1, bl, acc[1][q]);
            }
        }
    };

    for (int base = blockIdx.x * 64; base < total; base += gridDim.x * 64) {
        const int nrows = min(64, total - base);
        if (tid < 64) pl[tid] = (tid < nrows) ? pairs[base + tid] : make_int2(0, 0);
        __syncthreads();
        // ---- embed flagged pairs (8 threads per row), hi+lo planes ----
        {
            const int p   = tid >> 3;
            const int sub = tid & 7;
            const int2 pp = pl[p];
            const int b = pp.x;
            const float xw0 = x_world[b*3+0], xw1 = x_world[b*3+1], xw2 = x_world[b*3+2];
            const float* P = inv_poses + pp.y * 16;
            float xl[3];
            #pragma unroll
            for (int x = 0; x < 3; ++x)
                xl[x] = P[x*4+3] + P[x*4+0]*xw0 + P[x*4+1]*xw1 + P[x*4+2]*xw2;
            auto put = [&](int c, float v) {
                f16 hi = (f16)v;
                feath[p*40 + c] = hi;
                featl[p*40 + c] = (f16)(v - (float)hi);
            };
            if (sub == 0) {
                #pragma unroll
                for (int x = 0; x < 3; ++x) put(x, xl[x]);
                put(39, 0.f);
            }
            #pragma unroll
            for (int t = 0; t < 2; ++t) {
                int j = sub + 8*t;
                if (j < 12) {
                    int o = j >> 1, fn = j & 1;
                    float s = (float)(1 << o);
                    #pragma unroll
                    for (int x = 0; x < 3; ++x) {
                        float a = xl[x] * s;
                        put(3 + 6*o + 3*fn + x, fn ? cosf(a) : sinf(a));
                    }
                }
            }
        }
        __syncthreads();

        // ---- layer 0 (3-term) ----
        init_bias(b0);
        {
            const f16x8 z = {};
            #pragma unroll
            for (int kc = 0; kc < 2; ++kc) {
                f16x8 wh0 = *(const f16x8*)(wf + WS_W0H + ((wv*2     + kc)*64 + lane)*8);
                f16x8 wl0 = *(const f16x8*)(wf + WS_W0L + ((wv*2     + kc)*64 + lane)*8);
                f16x8 wh1 = *(const f16x8*)(wf + WS_W0H + (((wv+8)*2 + kc)*64 + lane)*8);
                f16x8 wl1 = *(const f16x8*)(wf + WS_W0L + (((wv+8)*2 + kc)*64 + lane)*8);
                #pragma unroll
                for (int q = 0; q < 4; ++q) {
                    int p = q * 16 + l15;
                    f16x8 ah, al;
                    if (kc == 0) {
                        ah = *(const f16x8*)&feath[p*40 + g*8];
                        al = *(const f16x8*)&featl[p*40 + g*8];
                    } else if (g == 0) {
                        ah = *(const f16x8*)&feath[p*40 + 32];
                        al = *(const f16x8*)&featl[p*40 + 32];
                    } else { ah = z; al = z; }
                    acc[0][q] = MFMA16(wh0, ah, acc[0][q]);
                    acc[0][q] = MFMA16(wl0, ah, acc[0][q]);
                    acc[0][q] = MFMA16(wh0, al, acc[0][q]);
                    acc[1][q] = MFMA16(wh1, ah, acc[1][q]);
                    acc[1][q] = MFMA16(wl1, ah, acc[1][q]);
                    acc[1][q] = MFMA16(wh1, al, acc[1][q]);
                }
            }
        }
        st_all2();                      // planes last read 2 syncs ago: safe
        __syncthreads();

        // ---- layer 1 ----
        init_bias(b1);
        hidden3(wf + WS_W1H, wf + WS_W1L);
        __syncthreads();
        st_all2();
        __syncthreads();

        // ---- layer 2 + layer 3 ----
        init_bias(b2);
        hidden3(wf + WS_W2H, wf + WS_W2L);
        {
            float pp4[4] = {};
            #pragma unroll
            for (int c2 = 0; c2 < 2; ++c2) {
                f32x4 wvv = *(const f32x4*)(w3 + (wv + c2*8) * 16 + g * 4);
                #pragma unroll
                for (int q = 0; q < 4; ++q)
                    #pragma unroll
                    for (int r = 0; r < 4; ++r)
                        pp4[q] = fmaf(fmaxf(acc[c2][q][r], 0.f), wvv[r], pp4[q]);
            }
            #pragma unroll
            for (int q = 0; q < 4; ++q) {
                pp4[q] += __shfl_xor(pp4[q], 16);
                pp4[q] += __shfl_xor(pp4[q], 32);
            }
            if (g == 0) {
                #pragma unroll
                for (int q = 0; q < 4; ++q)
                    predp[q * 16 + l15][wv] = pp4[q];
            }
        }
        __syncthreads();
        if (tid < nrows) {
            float s = b3[0];
            #pragma unroll
            for (int j = 0; j < 8; ++j) s += predp[tid][j];
            exact[pl[tid].x * NPOSE + pl[tid].y] = s;
        }
        __syncthreads();                // protect predp/pl before next chunk
    }
}

__global__ __launch_bounds__(128)
void fixup_kernel(const float* __restrict__ x_world,
                  const float* __restrict__ inv_poses,
                  const float* __restrict__ vector,
                  float* __restrict__ out,
                  const float* __restrict__ exact)
{
    const int b = blockIdx.x * 128 + threadIdx.x;
    if (b >= BPTS) return;

    const float* pr = out + OFF_PRED + (size_t)b * NPOSE;
    float best = pr[0], best2 = 3.4e38f;
    #pragma unroll
    for (int n = 1; n < NPOSE; ++n) {
        float v = pr[n];
        if (v < best) { best2 = best; best = v; }
        else if (v < best2) { best2 = v; }
    }
    if (best2 - best >= TAU) return;

    float ebest = 3.4e38f;
    int idx = 0;
    #pragma unroll
    for (int n = 0; n < NPOSE; ++n) {
        if (pr[n] < best + TAU) {
            float v = exact[b * NPOSE + n];
            if (v < ebest) { ebest = v; idx = n; }
        }
    }
    write_point(b, idx, x_world, inv_poses, vector, out);
}

extern "C" void kernel_launch(void* const* d_in, const int* in_sizes, int n_in,
                              void* d_out, int out_size, void* d_ws, size_t ws_size,
                              hipStream_t stream)
{
    const float* x_world   = (const float*)d_in[0];
    const float* inv_poses = (const float*)d_in[1];
    const float* vector    = (const float*)d_in[2];
    const float* w0 = (const float*)d_in[3];
    const float* b0 = (const float*)d_in[4];
    const float* w1 = (const float*)d_in[5];
    const float* b1 = (const float*)d_in[6];
    const float* w2 = (const float*)d_in[7];
    const float* b2 = (const float*)d_in[8];
    const float* w3 = (const float*)d_in[9];
    const float* b3 = (const float*)d_in[10];
    float* out = (float*)d_out;

    char*  ws    = (char*)d_ws;
    f16*   wf    = (f16*)ws;
    int*   cnt   = (int*)(ws + CNT_B);
    int2*  pairs = (int2*)(ws + PAIRS_B);
    float* exact = (float*)(ws + EXACT_B);

    prep_all<<<dim3(1136), dim3(256), 0, stream>>>(w0, w1, w2, wf, cnt);

    mlp_kernel<<<dim3(NPOSE * BPTS / TM), dim3(512), 0, stream>>>(
        x_world, inv_poses, b0, b1, b2, w3, b3, wf, out);
    select_kernel<<<dim3(BPTS / 128), dim3(128), 0, stream>>>(
        x_world, inv_poses, vector, out, cnt, pairs, exact);
    recompute_kernel<<<dim3(512), dim3(512), 0, stream>>>(
        x_world, inv_poses, b0, b1, b2, w3, b3, wf, cnt, pairs, exact);
    fixup_kernel<<<dim3(BPTS / 128), dim3(128), 0, stream>>>(
        x_world, inv_poses, vector, out, exact);
}